// Round 8
// baseline (468.253 us; speedup 1.0000x reference)
//
#include <hip/hip_runtime.h>
#include <cstdint>
#include <cstddef>

#define N_TOKENS 4096
#define HIDDEN   2048
#define INTER    1024
#define NE       8
#define NE_TOT   10
#define SCALE    2.5f

typedef short v8s __attribute__((ext_vector_type(8)));
typedef float v4f __attribute__((ext_vector_type(4)));

static __device__ inline int imin(int a, int b) { return a < b ? a : b; }

__device__ inline unsigned short f2bf(float f) {
  unsigned int u = __float_as_uint(f);
  u += 0x7fffu + ((u >> 16) & 1u);   // round-to-nearest-even
  return (unsigned short)(u >> 16);
}

__device__ inline uint4 f2bf8(float4 a0, float4 a1) {
  union { unsigned short u[8]; uint4 v; } r;
  r.u[0] = f2bf(a0.x); r.u[1] = f2bf(a0.y); r.u[2] = f2bf(a0.z); r.u[3] = f2bf(a0.w);
  r.u[4] = f2bf(a1.x); r.u[5] = f2bf(a1.y); r.u[6] = f2bf(a1.z); r.u[7] = f2bf(a1.w);
  return r.v;
}

__device__ inline void gld_lds16(const void* g, void* l) {
  __builtin_amdgcn_global_load_lds(
      (const __attribute__((address_space(1))) unsigned int*)g,
      (__attribute__((address_space(3))) unsigned int*)l, 16, 0, 0);
}

// ---------------- router: atomic-free, two-pass low-VGPR ----------------
// Slot assignment lives in partition_kernel (the R0-R5 ~101us invariant was
// 8192 serialized device-scope atomics on one counts[] line).
__global__ __launch_bounds__(256, 4) void router_kernel(
    const float* __restrict__ x, const float* __restrict__ rw,
    const float* __restrict__ bias, unsigned short* __restrict__ xb,
    signed char* __restrict__ tke, float* __restrict__ tkw,
    float* __restrict__ out) {
  int tid  = threadIdx.x;
  int lane = tid & 63;
  int wid  = tid >> 6;
  int n    = blockIdx.x * 4 + wid;

  const float* xr = x + (size_t)n * HIDDEN;
  float acc[NE_TOT];
#pragma unroll
  for (int e = 0; e < NE_TOT; e++) acc[e] = 0.f;

#pragma unroll 1
  for (int i = 0; i < 8; i++) {
    int k = (i * 64 + lane) * 4;
    float4 xv = *(const float4*)(xr + k);
#pragma unroll
    for (int e = 0; e < NE_TOT; e++) {
      float4 w = *(const float4*)(rw + (size_t)e * HIDDEN + k);
      acc[e] += xv.x * w.x + xv.y * w.y + xv.z * w.z + xv.w * w.w;
    }
  }
#pragma unroll
  for (int e = 0; e < NE_TOT; e++) {
    float v = acc[e];
#pragma unroll
    for (int off = 32; off > 0; off >>= 1) v += __shfl_xor(v, off, 64);
    acc[e] = v;  // all lanes hold the full dot product
  }

  // sigmoid + bias, top-2 (ties -> lower index), redundantly on all lanes
  float sc[NE_TOT], sb[NE_TOT];
#pragma unroll
  for (int e = 0; e < NE_TOT; e++) {
    sc[e] = 1.f / (1.f + expf(-acc[e]));
    sb[e] = sc[e] + bias[e];
  }
  int i1 = 0;
  for (int e = 1; e < NE_TOT; e++) if (sb[e] > sb[i1]) i1 = e;
  int i2 = (i1 == 0) ? 1 : 0;
  for (int e = 0; e < NE_TOT; e++) if (e != i1 && sb[e] > sb[i2]) i2 = e;
  float wzero = 0.f;
  if (i1 >= NE) wzero += sc[i1];
  if (i2 >= NE) wzero += sc[i2];
  if (lane == 0) {
    tke[n]            = (signed char)(i1 < NE ? i1 : -1);
    tke[N_TOKENS + n] = (signed char)(i2 < NE ? i2 : -1);
    tkw[n]            = i1 < NE ? SCALE * sc[i1] : 0.f;
    tkw[N_TOKENS + n] = i2 < NE ? SCALE * sc[i2] : 0.f;
  }
  float wz = SCALE * wzero;

  // pass 2: re-read x row (cache-hot), emit xb (bf16) and out = wz*x
#pragma unroll
  for (int i = 0; i < 8; i++) {
    int k = (i * 64 + lane) * 4;
    float4 xv = *(const float4*)(xr + k);
    ushort4 ob;
    ob.x = f2bf(xv.x); ob.y = f2bf(xv.y);
    ob.z = f2bf(xv.z); ob.w = f2bf(xv.w);
    *(ushort4*)(xb + (size_t)n * HIDDEN + k) = ob;
    float4 o;
    o.x = wz * xv.x; o.y = wz * xv.y; o.z = wz * xv.z; o.w = wz * xv.w;
    *(float4*)(out + (size_t)n * HIDDEN + k) = o;
  }
}

// ---------------- partition: deterministic slot assignment, no atomics ----------
__global__ __launch_bounds__(1024) void partition_kernel(
    const signed char* __restrict__ tke, int* __restrict__ tok_list,
    int* __restrict__ tkr, int* __restrict__ counts, int* __restrict__ offsets) {
  __shared__ int scn[1024][NE];   // 32 KB
  __shared__ int soff[NE];
  int tid = threadIdx.x;
  int t4  = tid * 4;

  int w0 = *(const int*)(tke + t4);             // picks tt=0, tokens t4..t4+3
  int w1 = *(const int*)(tke + N_TOKENS + t4);  // picks tt=1

#pragma unroll
  for (int e = 0; e < NE; e++) scn[tid][e] = 0;
#pragma unroll
  for (int i = 0; i < 4; i++) {
    int e0 = (int)(signed char)(w0 >> (8 * i));
    int e1 = (int)(signed char)(w1 >> (8 * i));
    if (e0 >= 0) scn[tid][e0]++;
    if (e1 >= 0) scn[tid][e1]++;
  }
  int c[NE], orig[NE];
#pragma unroll
  for (int e = 0; e < NE; e++) { c[e] = scn[tid][e]; orig[e] = c[e]; }
  __syncthreads();

  for (int s = 1; s < 1024; s <<= 1) {
    int v[NE];
    bool act = (tid >= s);
    if (act) {
#pragma unroll
      for (int e = 0; e < NE; e++) v[e] = scn[tid - s][e];
    }
    __syncthreads();
    if (act) {
#pragma unroll
      for (int e = 0; e < NE; e++) { c[e] += v[e]; scn[tid][e] = c[e]; }
    }
    __syncthreads();
  }

  if (tid == 0) {
    int s = 0;
#pragma unroll
    for (int e = 0; e < NE; e++) {
      int cnt = scn[1023][e];
      counts[e] = cnt; offsets[e] = s; soff[e] = s; s += cnt;
    }
  }
  __syncthreads();

  // own-row cursors: within-expert exclusive prefix for this thread
#pragma unroll
  for (int e = 0; e < NE; e++) scn[tid][e] = c[e] - orig[e];

#pragma unroll
  for (int i = 0; i < 4; i++) {
    int n  = t4 + i;
    int e0 = (int)(signed char)(w0 >> (8 * i));
    int e1 = (int)(signed char)(w1 >> (8 * i));
    if (e0 >= 0) {
      int slot = scn[tid][e0]++;
      tok_list[e0 * N_TOKENS + slot] = n;
      tkr[n] = soff[e0] + slot;
    } else tkr[n] = 0;
    if (e1 >= 0) {
      int slot = scn[tid][e1]++;
      tok_list[e1 * N_TOKENS + slot] = n;
      tkr[N_TOKENS + n] = soff[e1] + slot;
    } else tkr[N_TOKENS + n] = 0;
  }
}

// LDS xor-swizzle (kills 8-way ds_read_b128 bank conflicts):
// physical 16B chunk p of row r holds logical chunk p ^ ((r>>1)&3).
// Staging (lane tid -> row tid>>2, slot tid&3): fetch global chunk
// (tid&3) ^ ((tid>>3)&3). Readers: physical chunk (lane>>4) ^ ((lane>>1)&3).
//
// B is staged from the ORIGINAL f32 weights with on-the-fly f2bf conversion
// (2x global_load_dwordx4 -> cvt -> ds_write_b128 to the same swizzled LDS
// address gld_lds used). This removes the separate cvt pass (201 MB f32 read
// + 100 MB bf16 write per call). A keeps the fast global_load_lds path.
// Single-barrier loop stays correct: B writes hit buffer nxt whose readers
// completed before the previous barrier; __syncthreads drains vmcnt+lgkm.

// ---------------- gate_up grouped GEMM + fused SiLU*up (B: f32 on-the-fly) ----
__global__ __launch_bounds__(256, 4) void gateup_kernel(
    const unsigned short* __restrict__ xb, const float* __restrict__ wgu,
    const int* __restrict__ counts, const int* __restrict__ offsets,
    const int* __restrict__ tok_list, unsigned short* __restrict__ h_buf) {
  int jt = blockIdx.x;  // 16: f-block of 64
  int mt = blockIdx.y;  // 32: token tile of 128
  int e  = blockIdx.z;  // 8
  int count = counts[e];
  if (mt * 128 >= count) return;

  __shared__ unsigned short As[2][128 * 32];
  __shared__ unsigned short Bs[2][128 * 32];

  int tid  = threadIdx.x;
  int lane = tid & 63;
  int wm = (tid >> 7) & 1;
  int wn = (tid >> 6) & 1;

  int row0 = tid >> 2, row1 = row0 + 64;
  int col8 = (((tid & 3) ^ ((tid >> 3) & 3)) * 8);  // swizzled source chunk

  const int* tl = tok_list + e * N_TOKENS;
  int t0 = tl[imin(mt * 128 + row0, count - 1)];
  int t1 = tl[imin(mt * 128 + row1, count - 1)];
  const unsigned short* ag0 = xb + (size_t)t0 * HIDDEN + col8;
  const unsigned short* ag1 = xb + (size_t)t1 * HIDDEN + col8;

  int wn0 = row0 >> 6, wi0 = row0 & 63;
  int wn1 = row1 >> 6, wi1 = row1 & 63;
  int br0 = (wi0 < 32) ? (jt * 64 + wn0 * 32 + wi0) : (1024 + jt * 64 + wn0 * 32 + (wi0 - 32));
  int br1 = (wi1 < 32) ? (jt * 64 + wn1 * 32 + wi1) : (1024 + jt * 64 + wn1 * 32 + (wi1 - 32));
  const float* bbase = wgu + (size_t)e * (2 * INTER) * HIDDEN;
  const float* bg0 = bbase + (size_t)br0 * HIDDEN + col8;
  const float* bg1 = bbase + (size_t)br1 * HIDDEN + col8;

  v4f acc[4][4];
#pragma unroll
  for (int i = 0; i < 4; i++)
#pragma unroll
    for (int j = 0; j < 4; j++) acc[i][j] = v4f{0.f, 0.f, 0.f, 0.f};

  int mrow = wm * 64 + (lane & 15);
  int nrow = wn * 64 + (lane & 15);
  int kcol = (((lane >> 4) ^ ((lane >> 1) & 3)) * 8);  // swizzled read chunk

  // stage tile into buf: A via gld_lds, B via f32 reg-stage + cvt
#define GU_STAGE(buf)                                                        \
  do {                                                                       \
    gld_lds16(ag0, &As[buf][(size_t)tid * 8]);                               \
    gld_lds16(ag1, &As[buf][2048 + (size_t)tid * 8]);                        \
    float4 c0 = *(const float4*)bg0;                                         \
    float4 c1 = *(const float4*)(bg0 + 4);                                   \
    float4 d0 = *(const float4*)bg1;                                         \
    float4 d1 = *(const float4*)(bg1 + 4);                                   \
    *(uint4*)&Bs[buf][(size_t)tid * 8] = f2bf8(c0, c1);                      \
    *(uint4*)&Bs[buf][2048 + (size_t)tid * 8] = f2bf8(d0, d1);               \
    ag0 += 32; ag1 += 32; bg0 += 32; bg1 += 32;                              \
  } while (0)

  GU_STAGE(0);
  __syncthreads();

  const int NK = HIDDEN / 32;
  for (int kt = 0; kt < NK; kt++) {
    int cur = kt & 1;
    if (kt + 1 < NK) {
      int nxt = cur ^ 1;
      GU_STAGE(nxt);
    }
    v8s a[4], b[4];
#pragma unroll
    for (int i = 0; i < 4; i++) a[i] = *(const v8s*)&As[cur][(mrow + i * 16) * 32 + kcol];
#pragma unroll
    for (int j = 0; j < 4; j++) b[j] = *(const v8s*)&Bs[cur][(nrow + j * 16) * 32 + kcol];
#pragma unroll
    for (int i = 0; i < 4; i++)
#pragma unroll
      for (int j = 0; j < 4; j++)
        acc[i][j] = __builtin_amdgcn_mfma_f32_16x16x32_bf16(a[i], b[j], acc[i][j], 0, 0, 0);
    __syncthreads();
  }
#undef GU_STAGE

  int ocol  = lane & 15;
  int orow4 = (lane >> 4) * 4;
  int hoff  = offsets[e];
#pragma unroll
  for (int i = 0; i < 4; i++) {
#pragma unroll
    for (int r = 0; r < 4; r++) {
      int m = mt * 128 + wm * 64 + i * 16 + orow4 + r;
      if (m < count) {
        unsigned short* hrow = h_buf + (size_t)(hoff + m) * INTER;
#pragma unroll
        for (int j = 0; j < 2; j++) {
          float g = acc[i][j][r];
          float u = acc[i][j + 2][r];
          float hv = (g / (1.f + expf(-g))) * u;
          hrow[jt * 64 + wn * 32 + j * 16 + ocol] = f2bf(hv);
        }
      }
    }
  }
}

// ---------------- down grouped GEMM (B: f32 on-the-fly), stores y_buf ----------
__global__ __launch_bounds__(256, 4) void down_kernel(
    const unsigned short* __restrict__ h_buf, const float* __restrict__ wd,
    const int* __restrict__ counts, const int* __restrict__ offsets,
    float* __restrict__ y_buf) {
  int nt = blockIdx.x;  // 16: out-col tile of 128
  int mt = blockIdx.y;  // 32
  int e  = blockIdx.z;  // 8
  int count = counts[e];
  if (mt * 128 >= count) return;

  __shared__ unsigned short As[2][128 * 32];
  __shared__ unsigned short Bs[2][128 * 32];

  int tid  = threadIdx.x;
  int lane = tid & 63;
  int wm = (tid >> 7) & 1;
  int wn = (tid >> 6) & 1;

  int row0 = tid >> 2, row1 = row0 + 64;
  int col8 = (((tid & 3) ^ ((tid >> 3) & 3)) * 8);
  int hoff = offsets[e];

  const unsigned short* ag0 =
      h_buf + (size_t)(hoff + imin(mt * 128 + row0, count - 1)) * INTER + col8;
  const unsigned short* ag1 =
      h_buf + (size_t)(hoff + imin(mt * 128 + row1, count - 1)) * INTER + col8;
  const float* bbase = wd + (size_t)e * HIDDEN * INTER;
  const float* bg0 = bbase + (size_t)(nt * 128 + row0) * INTER + col8;
  const float* bg1 = bbase + (size_t)(nt * 128 + row1) * INTER + col8;

  v4f acc[4][4];
#pragma unroll
  for (int i = 0; i < 4; i++)
#pragma unroll
    for (int j = 0; j < 4; j++) acc[i][j] = v4f{0.f, 0.f, 0.f, 0.f};

  int mrow = wm * 64 + (lane & 15);
  int nrow = wn * 64 + (lane & 15);
  int kcol = (((lane >> 4) ^ ((lane >> 1) & 3)) * 8);

#define DN_STAGE(buf)                                                        \
  do {                                                                       \
    gld_lds16(ag0, &As[buf][(size_t)tid * 8]);                               \
    gld_lds16(ag1, &As[buf][2048 + (size_t)tid * 8]);                        \
    float4 c0 = *(const float4*)bg0;                                         \
    float4 c1 = *(const float4*)(bg0 + 4);                                   \
    float4 d0 = *(const float4*)bg1;                                         \
    float4 d1 = *(const float4*)(bg1 + 4);                                   \
    *(uint4*)&Bs[buf][(size_t)tid * 8] = f2bf8(c0, c1);                      \
    *(uint4*)&Bs[buf][2048 + (size_t)tid * 8] = f2bf8(d0, d1);               \
    ag0 += 32; ag1 += 32; bg0 += 32; bg1 += 32;                              \
  } while (0)

  DN_STAGE(0);
  __syncthreads();

  const int NK = INTER / 32;
  for (int kt = 0; kt < NK; kt++) {
    int cur = kt & 1;
    if (kt + 1 < NK) {
      int nxt = cur ^ 1;
      DN_STAGE(nxt);
    }
    v8s a[4], b[4];
#pragma unroll
    for (int i = 0; i < 4; i++) a[i] = *(const v8s*)&As[cur][(mrow + i * 16) * 32 + kcol];
#pragma unroll
    for (int j = 0; j < 4; j++) b[j] = *(const v8s*)&Bs[cur][(nrow + j * 16) * 32 + kcol];
#pragma unroll
    for (int i = 0; i < 4; i++)
#pragma unroll
      for (int j = 0; j < 4; j++)
        acc[i][j] = __builtin_amdgcn_mfma_f32_16x16x32_bf16(a[i], b[j], acc[i][j], 0, 0, 0);
    __syncthreads();
  }
#undef DN_STAGE

  int ocol  = lane & 15;
  int orow4 = (lane >> 4) * 4;
#pragma unroll
  for (int i = 0; i < 4; i++) {
#pragma unroll
    for (int r = 0; r < 4; r++) {
      int m = mt * 128 + wm * 64 + i * 16 + orow4 + r;
      if (m < count) {
        float* yrow = y_buf + (size_t)(hoff + m) * HIDDEN + nt * 128 + wn * 64 + ocol;
#pragma unroll
        for (int j = 0; j < 4; j++) yrow[j * 16] = acc[i][j][r];
      }
    }
  }
}

// ---------------- gather: out += w1*y[r1] + w2*y[r2], one token per wave ----
__global__ __launch_bounds__(256, 4) void gather_kernel(
    const float* __restrict__ y_buf, const int* __restrict__ tkr,
    const float* __restrict__ tkw, float* __restrict__ out) {
  int tid  = threadIdx.x;
  int lane = tid & 63;
  int wid  = tid >> 6;
  int n    = blockIdx.x * 4 + wid;

  int r1 = tkr[n], r2 = tkr[N_TOKENS + n];
  float w1 = tkw[n], w2 = tkw[N_TOKENS + n];
  const float* y1 = y_buf + (size_t)r1 * HIDDEN;
  const float* y2 = y_buf + (size_t)r2 * HIDDEN;
  float* orow = out + (size_t)n * HIDDEN;

#pragma unroll
  for (int i = 0; i < 8; i++) {
    int k = (i * 64 + lane) * 4;
    float4 o = *(const float4*)(orow + k);
    float4 a = *(const float4*)(y1 + k);
    float4 b = *(const float4*)(y2 + k);
    o.x += w1 * a.x + w2 * b.x;
    o.y += w1 * a.y + w2 * b.y;
    o.z += w1 * a.z + w2 * b.z;
    o.w += w1 * a.w + w2 * b.w;
    *(float4*)(orow + k) = o;
  }
}

extern "C" void kernel_launch(void* const* d_in, const int* in_sizes, int n_in,
                              void* d_out, int out_size, void* d_ws, size_t ws_size,
                              hipStream_t stream) {
  const float* x   = (const float*)d_in[0];
  const float* rw  = (const float*)d_in[1];
  const float* cb  = (const float*)d_in[2];
  const float* wgu = (const float*)d_in[3];
  const float* wd  = (const float*)d_in[4];
  float* out = (float*)d_out;

  char* ws = (char*)d_ws;
  size_t off = 0;
  auto alloc = [&](size_t bytes) {
    void* p = ws + off;
    off += (bytes + 255) & ~(size_t)255;
    return p;
  };
  unsigned short* xb    = (unsigned short*)alloc((size_t)N_TOKENS * HIDDEN * 2);
  unsigned short* h_buf = (unsigned short*)alloc((size_t)2 * N_TOKENS * INTER * 2);
  float* y_buf          = (float*)alloc((size_t)2 * N_TOKENS * HIDDEN * 4);
  int*   tok_list = (int*)alloc((size_t)NE * N_TOKENS * 4);
  signed char* tke = (signed char*)alloc((size_t)2 * N_TOKENS);
  int*   tkr      = (int*)alloc((size_t)2 * N_TOKENS * 4);
  float* tkw      = (float*)alloc((size_t)2 * N_TOKENS * 4);
  int*   counts   = (int*)alloc(256);
  int*   offsets  = (int*)alloc(256);
  (void)ws_size; (void)in_sizes; (void)n_in; (void)out_size;

  router_kernel<<<N_TOKENS / 4, 256, 0, stream>>>(x, rw, cb, xb, tke, tkw, out);
  partition_kernel<<<1, 1024, 0, stream>>>(tke, tok_list, tkr, counts, offsets);
  gateup_kernel<<<dim3(16, 32, 8), 256, 0, stream>>>(xb, wgu, counts, offsets, tok_list, h_buf);
  down_kernel<<<dim3(16, 32, 8), 256, 0, stream>>>(h_buf, wd, counts, offsets, y_buf);
  gather_kernel<<<N_TOKENS / 4, 256, 0, stream>>>(y_buf, tkr, tkw, out);
}